// Round 1
// baseline (229.250 us; speedup 1.0000x reference)
//
#include <hip/hip_runtime.h>
#include <math.h>

typedef __bf16 bf16;
typedef bf16 bf16x4 __attribute__((ext_vector_type(4)));
typedef bf16 bf16x8 __attribute__((ext_vector_type(8)));
typedef float f32x4 __attribute__((ext_vector_type(4)));

static_assert(sizeof(bf16x8) == 16, "bf16x8 must be 16B");

// q pre-scale: (1/sqrt(hd=32)) * log2(e)  -> softmax via exp2
#define QSCALE (0.17677669529663687f * 1.4426950408889634f)

__device__ __forceinline__ f32x4 mfma16(bf16x8 a, bf16x8 b, f32x4 c) {
  return __builtin_amdgcn_mfma_f32_16x16x32_bf16(a, b, c, 0, 0, 0);
}

// ---------------------------------------------------------------------------
// 0) weight prep: Wq->bf16, Wkv->bf16, w7 -> transposed fp32 w7t[tap][c]
//    grid = 32 (Wq) + 64 (Wkv) + 1 (w7t) = 97 blocks
// ---------------------------------------------------------------------------
__global__ __launch_bounds__(256) void k_cvt(
    const float* __restrict__ Wq, const float* __restrict__ Wkv,
    const float* __restrict__ w7, bf16* __restrict__ Wqb,
    bf16* __restrict__ Wkvb, float* __restrict__ w7t) {
  const int tid = threadIdx.x;
  const int blk = blockIdx.x;
  if (blk < 96) {
    const float* src;
    bf16* dst;
    if (blk < 32) {
      const int idx = blk * 256 + tid;            // Wq: 65536/8 = 8192
      src = Wq + (size_t)idx * 8;
      dst = Wqb + (size_t)idx * 8;
    } else {
      const int idx = (blk - 32) * 256 + tid;     // Wkv: 131072/8 = 16384
      src = Wkv + (size_t)idx * 8;
      dst = Wkvb + (size_t)idx * 8;
    }
    const float4 a = ((const float4*)src)[0];
    const float4 b = ((const float4*)src)[1];
    bf16x8 r;
    r[0] = (bf16)a.x; r[1] = (bf16)a.y; r[2] = (bf16)a.z; r[3] = (bf16)a.w;
    r[4] = (bf16)b.x; r[5] = (bf16)b.y; r[6] = (bf16)b.z; r[7] = (bf16)b.w;
    *(bf16x8*)dst = r;
  } else {
    const int c = tid;                            // w7t[tap*256+c] = w7[c*49+tap]
    #pragma unroll
    for (int tap = 0; tap < 49; tap++)
      w7t[tap * 256 + c] = w7[c * 49 + tap];
  }
}

// ---------------------------------------------------------------------------
// 1) dwconv 7x7 s4 p3 + BN1 + exact GELU + per-ch scale + BN2 -> kv1 (bf16)
//    branch-free: all 26 loads issued before any use (register arrays force
//    pipelining; a 12-VGPR body serializes 13 HBM latencies — r5 lesson).
// ---------------------------------------------------------------------------
__global__ __launch_bounds__(256) void k_sr(
    const float* __restrict__ x, const float* __restrict__ w7t,
    const float* __restrict__ g1, const float* __restrict__ b1,
    const float* __restrict__ m1, const float* __restrict__ v1,
    const float* __restrict__ sw2,
    const float* __restrict__ g2, const float* __restrict__ b2,
    const float* __restrict__ m2, const float* __restrict__ v2,
    bf16* __restrict__ kv1) {
  __shared__ float part[4][256];
  const int tid = threadIdx.x;
  const int team = tid >> 6, g = tid & 63;     // team = wave
  const int c0 = g * 4;
  const int blk = blockIdx.x;
  const int b = blk & 7, m = blk >> 3;
  const int oy = m >> 4, ox = m & 15;

  float4 xv[13], wv[13];
  float msk[13];
  #pragma unroll
  for (int j = 0; j < 13; j++) {               // issue ALL loads first
    const int tap = team + j * 4;
    const int ky = tap / 7, kx = tap - ky * 7;
    const int iy = oy * 4 - 3 + ky, ix = ox * 4 - 3 + kx;
    msk[j] = (tap < 49 && iy >= 0 && iy < 64 && ix >= 0 && ix < 64) ? 1.f : 0.f;
    const int iyc = iy < 0 ? 0 : (iy > 63 ? 63 : iy);
    const int ixc = ix < 0 ? 0 : (ix > 63 ? 63 : ix);
    const int tc = tap > 48 ? 48 : tap;
    xv[j] = *(const float4*)(x + ((size_t)b * 4096 + iyc * 64 + ixc) * 256 + c0);
    wv[j] = *(const float4*)(w7t + tc * 256 + c0);
  }
  float a0 = 0.f, a1 = 0.f, a2 = 0.f, a3 = 0.f;
  #pragma unroll
  for (int j = 0; j < 13; j++) {
    a0 += xv[j].x * wv[j].x * msk[j];
    a1 += xv[j].y * wv[j].y * msk[j];
    a2 += xv[j].z * wv[j].z * msk[j];
    a3 += xv[j].w * wv[j].w * msk[j];
  }
  *(f32x4*)&part[team][c0] = (f32x4){a0, a1, a2, a3};
  __syncthreads();
  const int c = tid;
  float y = part[0][c] + part[1][c] + part[2][c] + part[3][c];
  float s = g1[c] / sqrtf(v1[c] + 1e-5f);
  y = y * s + (b1[c] - m1[c] * s);
  y = 0.5f * y * (1.f + erff(y * 0.70710678118654752f));   // exact GELU
  y *= sw2[c];
  s = g2[c] / sqrtf(v2[c] + 1e-5f);
  y = y * s + (b2[c] - m2[c] * s);
  kv1[((size_t)b * 256 + m) * 256 + c] = (bf16)y;
}

// ---------------------------------------------------------------------------
// 2) FUSED local dw3x3(+bias+residual) + KV projection.
//    grid (32, B): block = 8 pixels. Halo in LDS -> conv -> fp32 rows -> GEMV.
//    dd<256 -> K (bh, m, hd) bf16; dd>=256 -> V^T (bh, hd, m)
// ---------------------------------------------------------------------------
__global__ __launch_bounds__(256) void k_localkv(
    const bf16* __restrict__ kv1, const float* __restrict__ w3,
    const float* __restrict__ lb, const bf16* __restrict__ Wkvb,
    const float* __restrict__ bkv, bf16* __restrict__ k_a,
    bf16* __restrict__ v_b) {
  __shared__ bf16 halo[3][10][256];
  __shared__ float rows[8][256];
  const int c = threadIdx.x;
  const int mt = blockIdx.x;   // 32 tiles of 8 pixels
  const int b = blockIdx.y;
  const int oy = mt >> 1, o0 = (mt & 1) * 8;

  #pragma unroll
  for (int p = 0; p < 30; p++) {
    const int dy = p / 10, xi = p - dy * 10;
    const int iy = oy - 1 + dy, ix = o0 - 1 + xi;
    const bool ok = (iy >= 0 && iy < 16 && ix >= 0 && ix < 16);
    const int iyc = ok ? iy : 0, ixc = ok ? ix : 0;
    const bf16 v = kv1[((size_t)b * 256 + iyc * 16 + ixc) * 256 + c];
    halo[dy][xi][c] = ok ? v : (bf16)0.f;
  }
  float w3f[9];
  #pragma unroll
  for (int t = 0; t < 9; t++) w3f[t] = w3[c * 9 + t];
  const float lbf = lb[c];
  __syncthreads();

  #pragma unroll
  for (int r = 0; r < 8; r++) {
    float acc = lbf + (float)halo[1][r + 1][c];   // bias + residual center
    #pragma unroll
    for (int ky = 0; ky < 3; ky++)
      #pragma unroll
      for (int kx = 0; kx < 3; kx++)
        acc += (float)halo[ky][r + kx][c] * w3f[ky * 3 + kx];
    rows[r][c] = acc;
  }
  __syncthreads();

  const int tid = c;
  float acck[8] = {0}, accv[8] = {0};
  for (int oc = 0; oc < 32; oc++) {
    const bf16x8 w0 = *(const bf16x8*)(Wkvb + (size_t)tid * 256 + oc * 8);
    const bf16x8 w1 = *(const bf16x8*)(Wkvb + ((size_t)tid + 256) * 256 + oc * 8);
    float wf0[8], wf1[8];
    #pragma unroll
    for (int j = 0; j < 8; j++) { wf0[j] = (float)w0[j]; wf1[j] = (float)w1[j]; }
    #pragma unroll
    for (int r = 0; r < 8; r++) {
      const float4* rp = (const float4*)&rows[r][oc * 8];
      const float4 ra = rp[0], rb = rp[1];
      const float rv[8] = {ra.x, ra.y, ra.z, ra.w, rb.x, rb.y, rb.z, rb.w};
      #pragma unroll
      for (int j = 0; j < 8; j++) {
        acck[r] += wf0[j] * rv[j];
        accv[r] += wf1[j] * rv[j];
      }
    }
  }
  const float bk = bkv[tid], bv = bkv[tid + 256];
  const int h = tid >> 5, d = tid & 31;
  #pragma unroll
  for (int r = 0; r < 8; r++) {
    const int m = (oy * 16 + o0) + r;
    k_a[(((size_t)b * 8 + h) * 256 + m) * 32 + d] = (bf16)(acck[r] + bk);
    v_b[(((size_t)b * 8 + h) * 32 + d) * 256 + m] = (bf16)(accv[r] + bv);
  }
}

// ---------------------------------------------------------------------------
// 3) FUSED q-projection + attention. grid (64, B), 256 thr = 4 waves.
//    Block owns 64 queries. Phase 1: stage x rows -> LDS bf16, MFMA-project
//    q (all 256 ch) exactly as the old k_qproj (same A/B/D layouts), apply
//    bias+QSCALE, write q back into the SAME LDS buffer (rows are
//    wave-private after the single barrier -> only ONE __syncthreads()).
//    Phase 2: per-head no-max softmax attention (verified r7 structure):
//    S^T = K.Q^T, p = exp2(s), O^T = V^T.P^T, normalize by sum.
//    Eliminates the q_ws HBM round-trip (33.5 MB) and one dispatch.
// ---------------------------------------------------------------------------
__global__ __launch_bounds__(256) void k_qattn(
    const float* __restrict__ x, const bf16* __restrict__ Wqb,
    const float* __restrict__ bq, const bf16* __restrict__ k_a,
    const bf16* __restrict__ v_b, float* __restrict__ out) {
  __shared__ bf16 qx[64 * 264];   // 264-elem row stride (528 B): 2-way banks
  const int tid = threadIdx.x, wv = tid >> 6, lane = tid & 63;
  const int qd = lane >> 4, l15 = lane & 15;
  const int b = blockIdx.y;
  const int n0 = blockIdx.x * 64;

  // ---- stage x (64 rows x 256 ch fp32) as bf16 into LDS ----
  #pragma unroll
  for (int it = 0; it < 8; it++) {
    const int idx = it * 256 + tid;
    const int lr = idx >> 5, pos = idx & 31;     // pos = 8-ch piece within row
    const float* src = x + ((size_t)b * 4096 + n0 + lr) * 256 + pos * 8;
    const float4 a = ((const float4*)src)[0];
    const float4 bb = ((const float4*)src)[1];
    bf16x8 r;
    r[0] = (bf16)a.x;  r[1] = (bf16)a.y;  r[2] = (bf16)a.z;  r[3] = (bf16)a.w;
    r[4] = (bf16)bb.x; r[5] = (bf16)bb.y; r[6] = (bf16)bb.z; r[7] = (bf16)bb.w;
    *(bf16x8*)(qx + lr * 264 + pos * 8) = r;
  }
  __syncthreads();   // the only barrier: after this, each wave touches only
                     // its own 16 LDS rows (reads af, writes q, reads qf)

  // ---- phase 1: q projection, wave = 16 rows x 256 cols ----
  bf16x8 af[8];
  #pragma unroll
  for (int kc = 0; kc < 8; kc++)
    af[kc] = *(const bf16x8*)(qx + (wv * 16 + l15) * 264 + kc * 32 + qd * 8);

  f32x4 acc[16];
  #pragma unroll
  for (int dt = 0; dt < 16; dt++) acc[dt] = (f32x4){0.f, 0.f, 0.f, 0.f};
  #pragma unroll
  for (int dt = 0; dt < 16; dt++) {
    #pragma unroll
    for (int kc = 0; kc < 8; kc++) {
      const bf16x8 bb =
          *(const bf16x8*)(Wqb + (size_t)(dt * 16 + l15) * 256 + kc * 32 + qd * 8);
      acc[dt] = mfma16(af[kc], bb, acc[dt]);
    }
  }
  // D layout: col=l15 -> channel d, row=qd*4+r -> query row (verified layout)
  #pragma unroll
  for (int dt = 0; dt < 16; dt++) {
    const int d = dt * 16 + l15;
    const float bias = bq[d];
    #pragma unroll
    for (int r = 0; r < 4; r++) {
      const int row = wv * 16 + qd * 4 + r;      // wave-private rows
      qx[row * 264 + d] = (bf16)((acc[dt][r] + bias) * QSCALE);
    }
  }

  // ---- phase 2: attention, wave = 16 queries, loop over 8 heads ----
  const bf16* kb = k_a + (size_t)(b * 8) * 256 * 32;
  const bf16* vb = v_b + (size_t)(b * 8) * 32 * 256;
  // permuted key row: A-tile t row l15 holds key 8*(l15>>2) + 4*t + (l15&3)
  const int kperm = 8 * (l15 >> 2) + (l15 & 3);
  const int nn = n0 + wv * 16 + l15;
  float* ob = out + ((size_t)b * 4096 + nn) * 256;

  for (int h = 0; h < 8; h++) {
    const bf16* kh = kb + (size_t)h * 256 * 32;
    const bf16* vh = vb + (size_t)h * 32 * 256;
    // B-operand: lane holds Q[d=qd*8+j][query=l15]
    const bf16x8 qf =
        *(const bf16x8*)(qx + (wv * 16 + l15) * 264 + h * 32 + qd * 8);
    f32x4 a0 = (f32x4){0.f, 0.f, 0.f, 0.f};
    f32x4 a1 = (f32x4){0.f, 0.f, 0.f, 0.f};
    float lr = 0.f;
    #pragma unroll
    for (int ch = 0; ch < 8; ch++) {             // 8 chunks x 32 keys
      const bf16x8 ka0 =
          *(const bf16x8*)(kh + (size_t)(ch * 32 + kperm) * 32 + qd * 8);
      const bf16x8 ka1 =
          *(const bf16x8*)(kh + (size_t)(ch * 32 + kperm + 4) * 32 + qd * 8);
      const bf16x8 va0 =
          *(const bf16x8*)(vh + (size_t)l15 * 256 + ch * 32 + qd * 8);
      const bf16x8 va1 =
          *(const bf16x8*)(vh + (size_t)(16 + l15) * 256 + ch * 32 + qd * 8);
      const f32x4 z = (f32x4){0.f, 0.f, 0.f, 0.f};
      // lane: scores for keys ch*32 + 8*qd + {0..3} (s0), +4+{0..3} (s1)
      f32x4 s0 = mfma16(ka0, qf, z);
      f32x4 s1 = mfma16(ka1, qf, z);
      float p[8];
      #pragma unroll
      for (int j = 0; j < 4; j++) {
        p[j] = __builtin_amdgcn_exp2f(fminf(s0[j], 80.f));
        p[4 + j] = __builtin_amdgcn_exp2f(fminf(s1[j], 80.f));
      }
      bf16x8 pb;                    // B-operand: k = qd*8+j == key-in-chunk
      #pragma unroll
      for (int j = 0; j < 8; j++) { lr += p[j]; pb[j] = (bf16)p[j]; }
      a0 = mfma16(va0, pb, a0);
      a1 = mfma16(va1, pb, a1);
    }
    lr += __shfl_xor(lr, 16, 64);
    lr += __shfl_xor(lr, 32, 64);
    const float inv = 1.f / lr;
    *(float4*)(ob + h * 32 + qd * 4) =
        (float4){a0[0] * inv, a0[1] * inv, a0[2] * inv, a0[3] * inv};
    *(float4*)(ob + h * 32 + 16 + qd * 4) =
        (float4){a1[0] * inv, a1[1] * inv, a1[2] * inv, a1[3] * inv};
  }
}

// ---------------------------------------------------------------------------
extern "C" void kernel_launch(void* const* d_in, const int* in_sizes, int n_in,
                              void* d_out, int out_size, void* d_ws, size_t ws_size,
                              hipStream_t stream) {
  const float* x      = (const float*)d_in[0];
  // d_in[1]=h, d_in[2]=w (64, 64) — compile-time constants here
  const float* Wq     = (const float*)d_in[3];
  const float* bq     = (const float*)d_in[4];
  const float* Wkv    = (const float*)d_in[5];
  const float* bkv    = (const float*)d_in[6];
  const float* sr_w1  = (const float*)d_in[7];
  const float* bn1_g  = (const float*)d_in[8];
  const float* bn1_b  = (const float*)d_in[9];
  const float* bn1_m  = (const float*)d_in[10];
  const float* bn1_v  = (const float*)d_in[11];
  const float* sw2    = (const float*)d_in[12];
  const float* bn2_g  = (const float*)d_in[13];
  const float* bn2_b  = (const float*)d_in[14];
  const float* bn2_m  = (const float*)d_in[15];
  const float* bn2_v  = (const float*)d_in[16];
  const float* lw     = (const float*)d_in[17];
  const float* lb     = (const float*)d_in[18];

  const int B = in_sizes[0] / (4096 * 256);   // = 8

  // workspace (~3 MB; d_ws is 256 MB per harness fill size):
  bf16* Wqb  = (bf16*)d_ws;                        // 65536 elems
  bf16* Wkvb = Wqb + 65536;                        // 131072 elems
  float* w7t = (float*)(Wkvb + 131072);            // 49*256 fp32
  bf16* kv1  = (bf16*)(w7t + 12544);               // (B,256,256)
  bf16* k_a  = kv1 + (size_t)B * 256 * 256;        // (bh,256,32)
  bf16* v_b  = k_a + (size_t)B * 8 * 256 * 32;     // (bh,32,256)

  k_cvt<<<dim3(97), 256, 0, stream>>>(Wq, Wkv, sr_w1, Wqb, Wkvb, w7t);
  k_sr<<<dim3(256 * B), 256, 0, stream>>>(x, w7t, bn1_g, bn1_b, bn1_m, bn1_v,
                                          sw2, bn2_g, bn2_b, bn2_m, bn2_v, kv1);
  k_localkv<<<dim3(32, B), 256, 0, stream>>>(kv1, lw, lb, Wkvb, bkv, k_a, v_b);
  k_qattn<<<dim3(64, B), 256, 0, stream>>>(x, Wqb, bq, k_a, v_b, (float*)d_out);
}